// Round 1
// baseline (998.696 us; speedup 1.0000x reference)
//
#include <hip/hip_runtime.h>

#define N_TOK  65536
#define N_CODE 8192
#define DIM    256

typedef _Float16 f16;
typedef _Float16 f16x8 __attribute__((ext_vector_type(8)));
typedef float    f32x4 __attribute__((ext_vector_type(4)));

// ---------- kernel 1: row sum-of-squares (one wave per row) ----------
// NOTE: summation order (float4 sequential + shfl_down tree) bit-matches the
// reference fp32 reduction — do not change.
__global__ __launch_bounds__(256) void rowsq_kernel(const float* __restrict__ src,
                                                    float* __restrict__ dst, int nrows) {
    int row  = blockIdx.x * 4 + (threadIdx.x >> 6);
    int lane = threadIdx.x & 63;
    if (row >= nrows) return;
    float4 v = ((const float4*)(src + (size_t)row * DIM))[lane];
    float s = v.x * v.x + v.y * v.y + v.z * v.z + v.w * v.w;
#pragma unroll
    for (int off = 32; off; off >>= 1) s += __shfl_down(s, off, 64);
    if (lane == 0) dst[row] = s;
}

// ---------- kernel 2: split W into 2 fp16 limbs (pre-scaled, subnormal-free) ----------
__global__ __launch_bounds__(256) void splitw_kernel(const float* __restrict__ W,
                                                     f16* __restrict__ W1,
                                                     f16* __restrict__ W2) {
    int f = blockIdx.x * 256 + threadIdx.x;          // float4 id
    float4 v = ((const float4*)W)[f];
    union { f16 h[4]; uint2 u; } p1, p2;
    float e[4] = {v.x, v.y, v.z, v.w};
#pragma unroll
    for (int i = 0; i < 4; ++i) {
        float ws = e[i] * 16384.0f;                  // exact (pow2)
        f16 w1 = (f16)ws;                            // RNE
        float r = (ws - (float)w1) * 2048.0f;        // exact
        p1.h[i] = w1; p2.h[i] = (f16)r;
    }
    ((uint2*)W1)[f] = p1.u;
    ((uint2*)W2)[f] = p2.u;
}

// ---------- kernel 3: fused MFMA GEMM + argmin, v3 ----------
// 256 blocks x 256 thr (4 waves, 1/SIMD at ~420 VGPR+AGPR). Wave owns 64
// tokens (mt=4); A-frags (both limbs, full K=256) persistent in 256 regs.
// Rationale vs v2: v2 was LDS-read-port bound (per CU-tile: 3072 cy LDS vs
// 1862 cy MFMA, near-serial). Doubling M/wave doubles B-frag reuse -> LDS
// reads/tile/CU halve (256 -> 128 ds_read_b128), MFMA becomes critical path.
// B (32-code stripes) streamed through a 2x32KB LDS double-buffer via
// global_load_lds(16) with XOR-permuted per-lane global addresses (unchanged
// staging scheme). Cross-limb terms share one accumulator chain (saves 32
// regs + 32 VALU/tile; delta-d ~1e-13 << 1.5e-5 d-grid, argmin-safe).
__global__ __launch_bounds__(256, 1) void argmin_mfma3(
    const float* __restrict__ X, const f16* __restrict__ W1, const f16* __restrict__ W2,
    const float* __restrict__ sxq, const float* __restrict__ esq,
    int* __restrict__ out_idx) {

    __shared__ char wbuf[65536];   // [sel:2][limb:2][16KB]

    const int tid  = threadIdx.x;
    const int lane = tid & 63;
    const int wv   = tid >> 6;        // 0..3
    const int cl   = lane & 15;       // code-col / token-row within 16
    const int q    = lane >> 4;       // 0..3 k-octet
    const int wavetok0 = blockIdx.x * 256 + wv * 64;

    // ---- A: load 64 tokens x 256 dims, split to 2 f16 limbs, keep in regs ----
    // frag (mt, s): lane holds X[wavetok0 + mt*16 + cl][s*32 + q*8 + j], j=0..7
    f16x8 a1[4][8], a2[4][8];
#pragma unroll
    for (int mt = 0; mt < 4; ++mt)
#pragma unroll
        for (int s = 0; s < 8; ++s) {
            const float* p = X + (size_t)(wavetok0 + mt * 16 + cl) * DIM + s * 32 + q * 8;
            float4 v0 = ((const float4*)p)[0];
            float4 v1 = ((const float4*)p)[1];
            float e[8] = {v0.x, v0.y, v0.z, v0.w, v1.x, v1.y, v1.z, v1.w};
#pragma unroll
            for (int j = 0; j < 8; ++j) {
                f16 h = (f16)e[j];
                float r = (e[j] - (float)h) * 2048.0f;   // exact
                a1[mt][s][j] = h;
                a2[mt][s][j] = (f16)r;
            }
        }

    // sx for this lane's 16 token slots: slot = mt*4+r -> token mt*16 + q*4 + r
    float sxr[16];
#pragma unroll
    for (int mt = 0; mt < 4; ++mt)
#pragma unroll
        for (int r = 0; r < 4; ++r)
            sxr[mt * 4 + r] = sxq[wavetok0 + mt * 16 + q * 4 + r];

    float bestd[16];
    int   besti[16];
#pragma unroll
    for (int i = 0; i < 16; ++i) { bestd[i] = 3.4e38f; besti[i] = 0x7fffffff; }

    // ---- staging: 32KB per ct (2 limbs x 32 codes x 512B), 32 wave-instrs, 8/wave.
    // lane i of instr fi: c = 2*cp + (i>>5), o = (i&31) ^ (c&7)
    // -> LDS linear layout seg(c,o) = c*32 + (o ^ (c&7))  (bank-conflict-limited reads)
    auto stage = [&](int ct2, int sel) {
#pragma unroll
        for (int t = 0; t < 8; ++t) {
            int fi = wv * 8 + t;
            int L  = fi >> 4;             // limb
            int cp = fi & 15;             // code pair
            int c  = 2 * cp + (lane >> 5);
            int o  = (lane & 31) ^ (c & 7);
            const f16* gsrc = (L ? W2 : W1) + (size_t)(ct2 * 32 + c) * DIM + o * 8;
            char* ldst = wbuf + sel * 32768 + L * 16384 + cp * 1024;
            __builtin_amdgcn_global_load_lds(
                (const __attribute__((address_space(1))) unsigned int*)gsrc,
                (__attribute__((address_space(3))) unsigned int*)ldst, 16, 0, 0);
        }
    };

    stage(0, 0);
    __syncthreads();

    for (int ct = 0; ct < N_CODE / 32; ++ct) {
        if (ct + 1 < N_CODE / 32) stage(ct + 1, (ct + 1) & 1);

        float se0 = esq[ct * 32 + cl];
        float se1 = esq[ct * 32 + 16 + cl];

        f32x4 mainA[4][2], cross[4][2];
#pragma unroll
        for (int mt = 0; mt < 4; ++mt)
#pragma unroll
            for (int nt = 0; nt < 2; ++nt) {
                mainA[mt][nt] = (f32x4){0.f, 0.f, 0.f, 0.f};
                cross[mt][nt] = (f32x4){0.f, 0.f, 0.f, 0.f};
            }

        const char* base = wbuf + (ct & 1) * 32768;
#pragma unroll
        for (int s = 0; s < 8; ++s) {
            f16x8 b1[2], b2[2];
#pragma unroll
            for (int nt = 0; nt < 2; ++nt) {
                int off = ((nt * 16 + cl) * 32 + (((s * 4 + q) ^ (cl & 7)))) * 16;
                b1[nt] = *(const f16x8*)(base + off);
                b2[nt] = *(const f16x8*)(base + 16384 + off);
            }
#pragma unroll
            for (int mt = 0; mt < 4; ++mt)
#pragma unroll
                for (int nt = 0; nt < 2; ++nt) {
                    mainA[mt][nt] = __builtin_amdgcn_mfma_f32_16x16x32_f16(a1[mt][s], b1[nt], mainA[mt][nt], 0, 0, 0);
                    cross[mt][nt] = __builtin_amdgcn_mfma_f32_16x16x32_f16(a2[mt][s], b1[nt], cross[mt][nt], 0, 0, 0);
                    cross[mt][nt] = __builtin_amdgcn_mfma_f32_16x16x32_f16(a1[mt][s], b2[nt], cross[mt][nt], 0, 0, 0);
                }
        }

        // epilogue: d = fl(fl(sx+se) - 2*dot); dot*2^14 = main + 2^-11*cross
        // per lane, candidates ascend in code (nt inner, ct outer): strict < keeps lowest.
#pragma unroll
        for (int mt = 0; mt < 4; ++mt)
#pragma unroll
            for (int nt = 0; nt < 2; ++nt)
#pragma unroll
                for (int r = 0; r < 4; ++r) {
                    float mc = fmaf(cross[mt][nt][r], 4.8828125e-4f, mainA[mt][nt][r]);  // *2^-11
                    float t1 = sxr[mt * 4 + r] + (nt ? se1 : se0);
                    float d  = fmaf(-1.220703125e-4f, mc, t1);                          // -2^-13
                    int slot = mt * 4 + r;
                    if (d < bestd[slot]) {
                        bestd[slot] = d;
                        besti[slot] = ct * 32 + nt * 16 + cl;
                    }
                }
        __syncthreads();
    }

    // ---- cross-lane reduction over the 16 code-lanes (lex (d, idx) min) ----
#pragma unroll
    for (int slot = 0; slot < 16; ++slot) {
        float d = bestd[slot];
        int   i = besti[slot];
#pragma unroll
        for (int off = 1; off < 16; off <<= 1) {
            float od = __shfl_xor(d, off, 64);
            int   oi = __shfl_xor(i, off, 64);
            if (od < d || (od == d && oi < i)) { d = od; i = oi; }
        }
        if (cl == 0)
            out_idx[wavetok0 + (slot >> 2) * 16 + q * 4 + (slot & 3)] = i;
    }
}

// ---------- kernel 4: gather + straight-through output + loss partials ----------
__global__ __launch_bounds__(256) void finalize_kernel(
    const float* __restrict__ X, const float* __restrict__ W,
    const int* __restrict__ idx, float* __restrict__ outQ,
    float* __restrict__ outI, double* __restrict__ accum) {
    __shared__ double wsum[4];
    int wid  = threadIdx.x >> 6;
    int lane = threadIdx.x & 63;
    int token = blockIdx.x * 4 + wid;
    int id = idx[token];
    float4 x = ((const float4*)(X + (size_t)token * DIM))[lane];
    float4 qv = ((const float4*)(W + (size_t)id * DIM))[lane];
    float4 o;
    o.x = x.x + (qv.x - x.x);
    o.y = x.y + (qv.y - x.y);
    o.z = x.z + (qv.z - x.z);
    o.w = x.w + (qv.w - x.w);
    ((float4*)(outQ + (size_t)token * DIM))[lane] = o;
    float dx = x.x - qv.x, dy = x.y - qv.y, dz = x.z - qv.z, dw = x.w - qv.w;
    float s = dx * dx + dy * dy + dz * dz + dw * dw;
#pragma unroll
    for (int off = 32; off; off >>= 1) s += __shfl_down(s, off, 64);
    if (lane == 0) {
        outI[token] = (float)id;
        wsum[wid] = (double)s;
    }
    __syncthreads();
    if (threadIdx.x == 0) {
        double t = wsum[0] + wsum[1] + wsum[2] + wsum[3];
        atomicAdd(accum, t);
    }
}

// ---------- kernel 5: scalars ----------
__global__ void scalars_kernel(const double* __restrict__ accum, float* __restrict__ out) {
    double mse = *accum / (double)((size_t)N_TOK * DIM);
    float c = (float)mse;
    out[0] = c + 0.25f * c;
    out[1] = c;
    out[2] = c;
}

extern "C" void kernel_launch(void* const* d_in, const int* in_sizes, int n_in,
                              void* d_out, int out_size, void* d_ws, size_t ws_size,
                              hipStream_t stream) {
    const float* X = (const float*)d_in[0];   // (65536, 256)
    const float* W = (const float*)d_in[1];   // (8192, 256)

    float* outQ = (float*)d_out;
    float* outI = outQ + (size_t)N_TOK * DIM;
    float* outS = outI + N_TOK;

    char* ws = (char*)d_ws;
    double* accum = (double*)ws;                         // @0
    float* esq = (float*)(ws + 64);                      // 32 KB
    float* sxq = (float*)(ws + 64 + 32768);              // 256 KB
    int*   idx = (int*)(ws + 64 + 32768 + 262144);       // 256 KB
    f16*   W1  = (f16*)(ws + (1 << 20));                 // 4 MB
    f16*   W2  = (f16*)(ws + (1 << 20) + 4194304);       // 4 MB

    hipMemsetAsync(accum, 0, sizeof(double), stream);
    splitw_kernel<<<N_CODE * DIM / 4 / 256, 256, 0, stream>>>(W, W1, W2);
    rowsq_kernel<<<N_CODE / 4, 256, 0, stream>>>(W, esq, N_CODE);
    rowsq_kernel<<<N_TOK / 4, 256, 0, stream>>>(X, sxq, N_TOK);
    argmin_mfma3<<<N_TOK / 256, 256, 0, stream>>>(X, W1, W2, sxq, esq, idx);
    finalize_kernel<<<N_TOK / 4, 256, 0, stream>>>(X, W, idx, outQ, outI, accum);
    scalars_kernel<<<1, 1, 0, stream>>>(accum, outS);
}

// Round 2
// 754.078 us; speedup vs baseline: 1.3244x; 1.3244x over previous
//
#include <hip/hip_runtime.h>

#define N_TOK  65536
#define N_CODE 8192
#define DIM    256

typedef _Float16 f16;
typedef _Float16 f16x8 __attribute__((ext_vector_type(8)));
typedef float    f32x4 __attribute__((ext_vector_type(4)));

// ---------- kernel 1: row sum-of-squares (one wave per row) ----------
// NOTE: summation order (float4 sequential + shfl_down tree) bit-matches the
// reference fp32 reduction — do not change.
__global__ __launch_bounds__(256) void rowsq_kernel(const float* __restrict__ src,
                                                    float* __restrict__ dst, int nrows) {
    int row  = blockIdx.x * 4 + (threadIdx.x >> 6);
    int lane = threadIdx.x & 63;
    if (row >= nrows) return;
    float4 v = ((const float4*)(src + (size_t)row * DIM))[lane];
    float s = v.x * v.x + v.y * v.y + v.z * v.z + v.w * v.w;
#pragma unroll
    for (int off = 32; off; off >>= 1) s += __shfl_down(s, off, 64);
    if (lane == 0) dst[row] = s;
}

// ---------- kernel 2: split W into 2 fp16 limbs (pre-scaled, subnormal-free) ----------
__global__ __launch_bounds__(256) void splitw_kernel(const float* __restrict__ W,
                                                     f16* __restrict__ W1,
                                                     f16* __restrict__ W2) {
    int f = blockIdx.x * 256 + threadIdx.x;          // float4 id
    float4 v = ((const float4*)W)[f];
    union { f16 h[4]; uint2 u; } p1, p2;
    float e[4] = {v.x, v.y, v.z, v.w};
#pragma unroll
    for (int i = 0; i < 4; ++i) {
        float ws = e[i] * 16384.0f;                  // exact (pow2)
        f16 w1 = (f16)ws;                            // RNE
        float r = (ws - (float)w1) * 2048.0f;        // exact
        p1.h[i] = w1; p2.h[i] = (f16)r;
    }
    ((uint2*)W1)[f] = p1.u;
    ((uint2*)W2)[f] = p2.u;
}

// ---------- kernel 3: fused MFMA GEMM + argmin, v4 ----------
// 512 blocks x 256 thr (4 waves, mt=2 -> 128 tokens/block), 2 blocks/CU.
// Rationale: v2 (680us) had 8 waves phase-locked in ONE block -> per-tile
// barrier/epilogue/ds-wait bubbles (~2600cy/tile, 40% overlap of LDS+MFMA).
// v3 (833us) showed mt=4 kills occupancy (1 wave/SIMD). v4 keeps 8 waves/CU
// (2/SIMD, A-frags 128 regs fit 2 waves) but as TWO independent blocks:
// block A's barrier drain overlaps block B's MFMA burst (m114 mechanism).
// Merged cross-limb accumulator chain (verified in v3, absmax 0.0) and
// s_setprio(1) around MFMA clusters (2-block phase diversity = T5 regime).
__global__ __launch_bounds__(256, 2) void argmin_mfma4(
    const float* __restrict__ X, const f16* __restrict__ W1, const f16* __restrict__ W2,
    const float* __restrict__ sxq, const float* __restrict__ esq,
    int* __restrict__ out_idx) {

    __shared__ char wbuf[65536];   // [sel:2][limb:2][16KB]

    const int tid  = threadIdx.x;
    const int lane = tid & 63;
    const int wv   = tid >> 6;        // 0..3
    const int cl   = lane & 15;       // code-col / token-row within 16
    const int q    = lane >> 4;       // 0..3 k-octet
    const int wavetok0 = blockIdx.x * 128 + wv * 32;

    // ---- A: load 32 tokens x 256 dims, split to 2 f16 limbs, keep in regs ----
    // frag (mt, s): lane holds X[wavetok0 + mt*16 + cl][s*32 + q*8 + j], j=0..7
    f16x8 a1[2][8], a2[2][8];
#pragma unroll
    for (int mt = 0; mt < 2; ++mt)
#pragma unroll
        for (int s = 0; s < 8; ++s) {
            const float* p = X + (size_t)(wavetok0 + mt * 16 + cl) * DIM + s * 32 + q * 8;
            float4 v0 = ((const float4*)p)[0];
            float4 v1 = ((const float4*)p)[1];
            float e[8] = {v0.x, v0.y, v0.z, v0.w, v1.x, v1.y, v1.z, v1.w};
#pragma unroll
            for (int j = 0; j < 8; ++j) {
                f16 h = (f16)e[j];
                float r = (e[j] - (float)h) * 2048.0f;   // exact
                a1[mt][s][j] = h;
                a2[mt][s][j] = (f16)r;
            }
        }

    // sx for this lane's 8 token slots: slot = mt*4+r -> token mt*16 + q*4 + r
    float sxr[8];
#pragma unroll
    for (int mt = 0; mt < 2; ++mt)
#pragma unroll
        for (int r = 0; r < 4; ++r)
            sxr[mt * 4 + r] = sxq[wavetok0 + mt * 16 + q * 4 + r];

    float bestd[8];
    int   besti[8];
#pragma unroll
    for (int i = 0; i < 8; ++i) { bestd[i] = 3.4e38f; besti[i] = 0x7fffffff; }

    // ---- staging: 32KB per ct (2 limbs x 32 codes x 512B), 32 wave-instrs, 8/wave.
    // lane i of instr fi: c = 2*cp + (i>>5), o = (i&31) ^ (c&7)
    // -> LDS linear layout seg(c,o) = c*32 + (o ^ (c&7))
    auto stage = [&](int ct2, int sel) {
#pragma unroll
        for (int t = 0; t < 8; ++t) {
            int fi = wv * 8 + t;
            int L  = fi >> 4;             // limb
            int cp = fi & 15;             // code pair
            int c  = 2 * cp + (lane >> 5);
            int o  = (lane & 31) ^ (c & 7);
            const f16* gsrc = (L ? W2 : W1) + (size_t)(ct2 * 32 + c) * DIM + o * 8;
            char* ldst = wbuf + sel * 32768 + L * 16384 + cp * 1024;
            __builtin_amdgcn_global_load_lds(
                (const __attribute__((address_space(1))) unsigned int*)gsrc,
                (__attribute__((address_space(3))) unsigned int*)ldst, 16, 0, 0);
        }
    };

    stage(0, 0);
    __syncthreads();

    for (int ct = 0; ct < N_CODE / 32; ++ct) {
        if (ct + 1 < N_CODE / 32) stage(ct + 1, (ct + 1) & 1);

        float se0 = esq[ct * 32 + cl];
        float se1 = esq[ct * 32 + 16 + cl];

        f32x4 mainA[2][2], cross[2][2];
#pragma unroll
        for (int mt = 0; mt < 2; ++mt)
#pragma unroll
            for (int nt = 0; nt < 2; ++nt) {
                mainA[mt][nt] = (f32x4){0.f, 0.f, 0.f, 0.f};
                cross[mt][nt] = (f32x4){0.f, 0.f, 0.f, 0.f};
            }

        const char* base = wbuf + (ct & 1) * 32768;
#pragma unroll
        for (int s = 0; s < 8; ++s) {
            f16x8 b1[2], b2[2];
#pragma unroll
            for (int nt = 0; nt < 2; ++nt) {
                int off = ((nt * 16 + cl) * 32 + (((s * 4 + q) ^ (cl & 7)))) * 16;
                b1[nt] = *(const f16x8*)(base + off);
                b2[nt] = *(const f16x8*)(base + 16384 + off);
            }
            __builtin_amdgcn_s_setprio(1);
#pragma unroll
            for (int mt = 0; mt < 2; ++mt)
#pragma unroll
                for (int nt = 0; nt < 2; ++nt) {
                    mainA[mt][nt] = __builtin_amdgcn_mfma_f32_16x16x32_f16(a1[mt][s], b1[nt], mainA[mt][nt], 0, 0, 0);
                    cross[mt][nt] = __builtin_amdgcn_mfma_f32_16x16x32_f16(a2[mt][s], b1[nt], cross[mt][nt], 0, 0, 0);
                    cross[mt][nt] = __builtin_amdgcn_mfma_f32_16x16x32_f16(a1[mt][s], b2[nt], cross[mt][nt], 0, 0, 0);
                }
            __builtin_amdgcn_s_setprio(0);
        }

        // epilogue: d = fl(fl(sx+se) - 2*dot); dot*2^14 = main + 2^-11*cross
        // per lane, candidates ascend in code (nt inner, ct outer): strict < keeps lowest.
#pragma unroll
        for (int mt = 0; mt < 2; ++mt)
#pragma unroll
            for (int nt = 0; nt < 2; ++nt)
#pragma unroll
                for (int r = 0; r < 4; ++r) {
                    float mc = fmaf(cross[mt][nt][r], 4.8828125e-4f, mainA[mt][nt][r]);  // *2^-11
                    float t1 = sxr[mt * 4 + r] + (nt ? se1 : se0);
                    float d  = fmaf(-1.220703125e-4f, mc, t1);                          // -2^-13
                    int slot = mt * 4 + r;
                    if (d < bestd[slot]) {
                        bestd[slot] = d;
                        besti[slot] = ct * 32 + nt * 16 + cl;
                    }
                }
        __syncthreads();
    }

    // ---- cross-lane reduction over the 16 code-lanes (lex (d, idx) min) ----
#pragma unroll
    for (int slot = 0; slot < 8; ++slot) {
        float d = bestd[slot];
        int   i = besti[slot];
#pragma unroll
        for (int off = 1; off < 16; off <<= 1) {
            float od = __shfl_xor(d, off, 64);
            int   oi = __shfl_xor(i, off, 64);
            if (od < d || (od == d && oi < i)) { d = od; i = oi; }
        }
        if (cl == 0)
            out_idx[wavetok0 + (slot >> 2) * 16 + q * 4 + (slot & 3)] = i;
    }
}

// ---------- kernel 4: gather + straight-through output + loss partials ----------
// atomic spread over 128 accumulators: 16384 same-address f64 atomics serialize
// at one TCC slice (~15ns each ~ 250us); 128 addresses -> ~128 deep each.
__global__ __launch_bounds__(256) void finalize_kernel(
    const float* __restrict__ X, const float* __restrict__ W,
    const int* __restrict__ idx, float* __restrict__ outQ,
    float* __restrict__ outI, double* __restrict__ accum) {
    __shared__ double wsum[4];
    int wid  = threadIdx.x >> 6;
    int lane = threadIdx.x & 63;
    int token = blockIdx.x * 4 + wid;
    int id = idx[token];
    float4 x = ((const float4*)(X + (size_t)token * DIM))[lane];
    float4 qv = ((const float4*)(W + (size_t)id * DIM))[lane];
    float4 o;
    o.x = x.x + (qv.x - x.x);
    o.y = x.y + (qv.y - x.y);
    o.z = x.z + (qv.z - x.z);
    o.w = x.w + (qv.w - x.w);
    ((float4*)(outQ + (size_t)token * DIM))[lane] = o;
    float dx = x.x - qv.x, dy = x.y - qv.y, dz = x.z - qv.z, dw = x.w - qv.w;
    float s = dx * dx + dy * dy + dz * dz + dw * dw;
#pragma unroll
    for (int off = 32; off; off >>= 1) s += __shfl_down(s, off, 64);
    if (lane == 0) {
        outI[token] = (float)id;
        wsum[wid] = (double)s;
    }
    __syncthreads();
    if (threadIdx.x == 0) {
        double t = wsum[0] + wsum[1] + wsum[2] + wsum[3];
        atomicAdd(&accum[blockIdx.x & 127], t);
    }
}

// ---------- kernel 5: scalars ----------
__global__ void scalars_kernel(const double* __restrict__ accum, float* __restrict__ out) {
    double mse = 0.0;
    for (int i = 0; i < 128; ++i) mse += accum[i];
    mse /= (double)((size_t)N_TOK * DIM);
    float c = (float)mse;
    out[0] = c + 0.25f * c;
    out[1] = c;
    out[2] = c;
}

extern "C" void kernel_launch(void* const* d_in, const int* in_sizes, int n_in,
                              void* d_out, int out_size, void* d_ws, size_t ws_size,
                              hipStream_t stream) {
    const float* X = (const float*)d_in[0];   // (65536, 256)
    const float* W = (const float*)d_in[1];   // (8192, 256)

    float* outQ = (float*)d_out;
    float* outI = outQ + (size_t)N_TOK * DIM;
    float* outS = outI + N_TOK;

    char* ws = (char*)d_ws;
    double* accum = (double*)ws;                         // @0, 1 KB (128 doubles)
    float* esq = (float*)(ws + 4096);                    // 32 KB
    float* sxq = (float*)(ws + 4096 + 32768);            // 256 KB
    int*   idx = (int*)(ws + 4096 + 32768 + 262144);     // 256 KB
    f16*   W1  = (f16*)(ws + (1 << 20));                 // 4 MB
    f16*   W2  = (f16*)(ws + (1 << 20) + 4194304);       // 4 MB

    hipMemsetAsync(accum, 0, 128 * sizeof(double), stream);
    splitw_kernel<<<N_CODE * DIM / 4 / 256, 256, 0, stream>>>(W, W1, W2);
    rowsq_kernel<<<N_CODE / 4, 256, 0, stream>>>(W, esq, N_CODE);
    rowsq_kernel<<<N_TOK / 4, 256, 0, stream>>>(X, sxq, N_TOK);
    argmin_mfma4<<<N_TOK / 128, 256, 0, stream>>>(X, W1, W2, sxq, esq, idx);
    finalize_kernel<<<N_TOK / 4, 256, 0, stream>>>(X, W, idx, outQ, outI, accum);
    scalars_kernel<<<1, 1, 0, stream>>>(accum, outS);
}